// Round 11
// baseline (94.507 us; speedup 1.0000x reference)
//
#include <hip/hip_runtime.h>

#define NFULL 8192
#define BATCH 4
#define NPTS (NFULL * BATCH)             // 32768 points total
#define TT 256                           // square tile side
#define NT (NFULL / TT)                  // 32 tiles per dim
#define JOBS_PER_B (NT * (NT + 1) / 2)   // 528 triangular tile pairs
#define TOTAL_JOBS (BATCH * JOBS_PER_B)  // 2112
#define IR 4                             // i-points per lane (64*4 = 256 = TT)
#define IR2 (IR / 2)                     // f32x2 pairs per lane
#define JW 64                            // j-points per wave (4 waves * 64 = TT)
#define LAMBDA 0.001

typedef float f32x2 __attribute__((ext_vector_type(2)));

// ws layout: float4 pts | float w | float partials  (~648 KB)
#define WS_PTS_OFF   0
#define WS_W_OFF     (NPTS * 16)
#define WS_PART_OFF  (WS_W_OFF + NPTS * 4)

__device__ __forceinline__ float bcast(float v, int lane) {
    return __int_as_float(__builtin_amdgcn_readlane(__float_as_int(v), lane));
}

// ---- prep: materialize per-point derived values once --------------------
__global__ __launch_bounds__(256)
void KUNi_prep(const float* __restrict__ inputs,
               const float* __restrict__ coords,
               float4* __restrict__ pts,
               float* __restrict__ wts) {
    const int idx = blockIdx.x * 256 + threadIdx.x;    // 0..NPTS-1
    const int b = idx >> 13;                           // /8192
    const int n = idx & (NFULL - 1);
    const float* cp = coords + (size_t)idx * 3;
    const float x = cp[0], y = cp[1], z = cp[2];
    const float sq = fmaf(x, x, fmaf(y, y, z * z));
    const float a0 = inputs[(size_t)b * 2 * NFULL + n];
    const float a1 = inputs[(size_t)b * 2 * NFULL + NFULL + n];
    const float w = 1.0f / (1.0f + __expf(a0 - a1));   // softmax(C=2)[1]
    pts[idx] = make_float4(x, y, z, sq);
    wts[idx] = w;
}

__global__ void KUNi_finalize(const float* __restrict__ partials,
                              float* __restrict__ out) {
    const int tid = threadIdx.x;          // 256
    const int lane = tid & 63, wv = tid >> 6;
    double s = 0.0;
    for (int i = tid; i < TOTAL_JOBS; i += 256) s += (double)partials[i];
#pragma unroll
    for (int off = 32; off > 0; off >>= 1) s += __shfl_xor(s, off, 64);
    __shared__ double sd[4];
    if (lane == 0) sd[wv] = s;
    __syncthreads();
    if (tid == 0) {
        const double scale = LAMBDA / ((double)BATCH * (double)NFULL * (double)NFULL);
        out[0] = (float)((sd[0] + sd[1] + sd[2] + sd[3]) * scale);
    }
}

__device__ __forceinline__ int tri_off(int t) {        // row start of row t
    return t * (2 * NT + 1 - t) / 2;
}

__global__ __launch_bounds__(256)
void KUNi_dpp_kernel(const float4* __restrict__ pts,
                     const float* __restrict__ wts,
                     float* __restrict__ partials) {
    __shared__ float sred[4];

    const int tid = threadIdx.x;         // 0..255
    const int lane = tid & 63;
    const int wv = tid >> 6;             // wave 0..3
    const int bid = blockIdx.x;          // 0..2111
    const int b = bid / JOBS_PER_B;
    const int p = bid - b * JOBS_PER_B;

    // closed-form triangular decode (ti <= tj), float sqrt + exact fixup
    const float q = (float)(2 * NT + 1); // 65
    int ti = (int)floorf((q - sqrtf(fmaf(-8.0f, (float)p, q * q))) * 0.5f);
    if (p < tri_off(ti)) --ti;
    else if (p >= tri_off(ti + 1)) ++ti;
    const int tj = ti + (p - tri_off(ti));
    const int base = b * NFULL;

    // ---- each lane owns IR i-points, packed f32x2 SoA; xyz pre-scaled ---
    // by -2 so the inner fma computes  sq_i + sq_j - 2*c_i.c_j  with raw j.
    f32x2 ix2[IR2], iy2[IR2], iz2[IR2], isq2[IR2], iw2[IR2], acc2[IR2];
    const int ibase = base + ti * TT + lane;
#pragma unroll
    for (int k = 0; k < IR2; ++k) {
        const float4 p0 = pts[ibase + (2 * k) * 64];
        const float4 p1 = pts[ibase + (2 * k + 1) * 64];
        ix2[k]  = (f32x2){-2.0f * p0.x, -2.0f * p1.x};
        iy2[k]  = (f32x2){-2.0f * p0.y, -2.0f * p1.y};
        iz2[k]  = (f32x2){-2.0f * p0.z, -2.0f * p1.z};
        isq2[k] = (f32x2){p0.w, p1.w};
        iw2[k]  = (f32x2){wts[ibase + (2 * k) * 64],
                          wts[ibase + (2 * k + 1) * 64]};
        acc2[k] = (f32x2){0.0f, 0.0f};
    }

    // ---- this wave's 64 j-points live in 5 VGPRs (lane l = j-point l) ---
    const int j0 = wv * JW;
    const float4 jreg = pts[base + tj * TT + j0 + lane];   // raw {x,y,z,sq}
    const float jwreg = wts[base + tj * TT + j0 + lane];

    // ---- inner loop: j broadcast via v_readlane (no memory at all) ------
#pragma unroll 8
    for (int jj = 0; jj < JW; ++jj) {
        const float jx  = bcast(jreg.x, jj);
        const float jy  = bcast(jreg.y, jj);
        const float jz  = bcast(jreg.z, jj);
        const float jsq = bcast(jreg.w, jj);
        const float jw  = bcast(jwreg,  jj);
#pragma unroll
        for (int k = 0; k < IR2; ++k) {
            f32x2 t = isq2[k] + jsq;                       // v_pk_add_f32
            t = __builtin_elementwise_fma(ix2[k], (f32x2){jx, jx}, t);
            t = __builtin_elementwise_fma(iy2[k], (f32x2){jy, jy}, t);
            t = __builtin_elementwise_fma(iz2[k], (f32x2){jz, jz}, t);
            t = __builtin_elementwise_max(t, (f32x2){0.0f, 0.0f});
            f32x2 s;
            s.x = __builtin_amdgcn_sqrtf(t.x);             // v_sqrt_f32
            s.y = __builtin_amdgcn_sqrtf(t.y);
            acc2[k] = __builtin_elementwise_fma(s, (f32x2){jw, jw}, acc2[k]);
        }
    }

    // ---- fold w_i, weight off-diagonal tiles by 2 (symmetry) ------------
    f32x2 vv = iw2[0] * acc2[0];
#pragma unroll
    for (int k = 1; k < IR2; ++k)
        vv = __builtin_elementwise_fma(iw2[k], acc2[k], vv);
    float v = vv.x + vv.y;
    if (ti != tj) v *= 2.0f;

    // ---- wave butterfly, cross-wave via LDS, one store per block --------
#pragma unroll
    for (int off = 32; off > 0; off >>= 1) v += __shfl_xor(v, off, 64);
    if (lane == 0) sred[wv] = v;
    __syncthreads();
    if (tid == 0) partials[bid] = sred[0] + sred[1] + sred[2] + sred[3];
}

extern "C" void kernel_launch(void* const* d_in, const int* in_sizes, int n_in,
                              void* d_out, int out_size, void* d_ws, size_t ws_size,
                              hipStream_t stream) {
    const float* inputs = (const float*)d_in[0];   // (4, 2, 8192) f32
    const float* coords = (const float*)d_in[1];   // (4, 8192, 3) f32
    float* out = (float*)d_out;                    // scalar f32
    char* ws = (char*)d_ws;
    float4* pts = (float4*)(ws + WS_PTS_OFF);
    float* wts = (float*)(ws + WS_W_OFF);
    float* partials = (float*)(ws + WS_PART_OFF);

    KUNi_prep<<<NPTS / 256, 256, 0, stream>>>(inputs, coords, pts, wts);
    KUNi_dpp_kernel<<<TOTAL_JOBS, 256, 0, stream>>>(pts, wts, partials);
    KUNi_finalize<<<1, 256, 0, stream>>>(partials, out);
}

// Round 12
// 87.946 us; speedup vs baseline: 1.0746x; 1.0746x over previous
//
#include <hip/hip_runtime.h>

#define NFULL 8192
#define BATCH 4
#define NPTS (NFULL * BATCH)             // 32768 points total
#define TT 256                           // tile side
#define NT (NFULL / TT)                  // 32 tiles per dim
#define BLOCKS_PER_B 272                 // sum of ceil((tj+1)/2), tj=0..31
#define TOTAL_BLOCKS (BATCH * BLOCKS_PER_B)  // 1088
#define IR2 4                            // f32x2 regs: .x = i-tile0, .y = i-tile1
#define JW 64                            // j-points per wave (4 waves * 64 = TT)
#define LAMBDA 0.001

typedef float f32x2 __attribute__((ext_vector_type(2)));

// ws layout: float4 pts | float w | float partials  (~648 KB)
#define WS_PTS_OFF   0
#define WS_W_OFF     (NPTS * 16)
#define WS_PART_OFF  (WS_W_OFF + NPTS * 4)

// ---- prep: materialize per-point derived values once --------------------
__global__ __launch_bounds__(256)
void KUNi_prep(const float* __restrict__ inputs,
               const float* __restrict__ coords,
               float4* __restrict__ pts,
               float* __restrict__ wts) {
    const int idx = blockIdx.x * 256 + threadIdx.x;    // 0..NPTS-1
    const int b = idx >> 13;                           // /8192
    const int n = idx & (NFULL - 1);
    const float* cp = coords + (size_t)idx * 3;
    const float x = cp[0], y = cp[1], z = cp[2];
    const float sq = fmaf(x, x, fmaf(y, y, z * z));
    const float a0 = inputs[(size_t)b * 2 * NFULL + n];
    const float a1 = inputs[(size_t)b * 2 * NFULL + NFULL + n];
    const float w = 1.0f / (1.0f + __expf(a0 - a1));   // softmax(C=2)[1]
    pts[idx] = make_float4(x, y, z, sq);
    wts[idx] = w;
}

__global__ void KUNi_finalize(const float* __restrict__ partials,
                              float* __restrict__ out) {
    const int tid = threadIdx.x;          // 256
    const int lane = tid & 63, wv = tid >> 6;
    double s = 0.0;
    for (int i = tid; i < TOTAL_BLOCKS; i += 256) s += (double)partials[i];
#pragma unroll
    for (int off = 32; off > 0; off >>= 1) s += __shfl_xor(s, off, 64);
    __shared__ double sd[4];
    if (lane == 0) sd[wv] = s;
    __syncthreads();
    if (tid == 0) {
        const double scale = LAMBDA / ((double)BATCH * (double)NFULL * (double)NFULL);
        out[0] = (float)((sd[0] + sd[1] + sd[2] + sd[3]) * scale);
    }
}

// Each block: one j-tile (tj) vs TWO i-tiles (ti0=2m, ti1=2m+1) from column
// tj. Every LDS j-broadcast feeds 512 pairs (2x the old rate). Odd column
// lengths: duplicate ti0 in the .y half with fold-weight 0.
__global__ __launch_bounds__(256)
void KUNi_dpp_kernel(const float4* __restrict__ pts,
                     const float* __restrict__ wts,
                     float* __restrict__ partials) {
    __shared__ float4 sjA[TT];           // {-2x, -2y, -2z, sq}
    __shared__ float sw[TT];             // w_j (read as float4 groups)
    __shared__ float sred[4];

    const int tid = threadIdx.x;         // 0..255
    const int lane = tid & 63;
    const int wv = tid >> 6;             // wave 0..3
    const int bid = blockIdx.x;          // 0..1087
    const int b = bid / BLOCKS_PER_B;
    int r = bid - b * BLOCKS_PER_B;      // 0..271

    // decode r -> (tj, m): column tj holds ceil((tj+1)/2) blocks
    int tj = 0;
    while (r >= ((tj + 2) >> 1)) { r -= (tj + 2) >> 1; ++tj; }
    const int ti0 = 2 * r;
    const int t1v = 2 * r + 1;
    const bool v1 = (t1v <= tj);
    const int ti1 = v1 ? t1v : ti0;
    const float fac0 = (ti0 != tj) ? 2.0f : 1.0f;
    const float fac1 = v1 ? ((t1v != tj) ? 2.0f : 1.0f) : 0.0f;
    const int base = b * NFULL;

    // ---- stage j-tile into LDS with -2 prescale -------------------------
    {
        const float4 jp = pts[base + tj * TT + tid];
        sjA[tid] = make_float4(-2.0f * jp.x, -2.0f * jp.y, -2.0f * jp.z, jp.w);
        sw[tid] = wts[base + tj * TT + tid];
    }

    // ---- i registers: .x from tile ti0, .y from tile ti1 ----------------
    f32x2 ix2[IR2], iy2[IR2], iz2[IR2], isq2[IR2], iw2[IR2], acc2[IR2];
    const int ia = base + ti0 * TT + lane;
    const int ib = base + ti1 * TT + lane;
#pragma unroll
    for (int k = 0; k < IR2; ++k) {
        const float4 p0 = pts[ia + k * 64];
        const float4 p1 = pts[ib + k * 64];
        ix2[k]  = (f32x2){p0.x, p1.x};
        iy2[k]  = (f32x2){p0.y, p1.y};
        iz2[k]  = (f32x2){p0.z, p1.z};
        isq2[k] = (f32x2){p0.w, p1.w};
        iw2[k]  = (f32x2){wts[ia + k * 64], wts[ib + k * 64]};
        acc2[k] = (f32x2){0.0f, 0.0f};
    }

    __syncthreads();

    // ---- wave's 64-j chunk: 5 LDS reads per 4 jj, 512 pairs per jj ------
    const int j0 = wv * JW;
#pragma unroll 2
    for (int g = 0; g < JW / 4; ++g) {
        const float4 w4 = *(const float4*)&sw[j0 + 4 * g];   // ds_read_b128
#pragma unroll
        for (int u = 0; u < 4; ++u) {
            const float4 jv = sjA[j0 + 4 * g + u];           // ds_read_b128
            const float jw = (&w4.x)[u];
#pragma unroll
            for (int k = 0; k < IR2; ++k) {
                f32x2 t = isq2[k] + jv.w;                    // v_pk_add_f32
                t = __builtin_elementwise_fma(ix2[k], (f32x2){jv.x, jv.x}, t);
                t = __builtin_elementwise_fma(iy2[k], (f32x2){jv.y, jv.y}, t);
                t = __builtin_elementwise_fma(iz2[k], (f32x2){jv.z, jv.z}, t);
                t = __builtin_elementwise_max(t, (f32x2){0.0f, 0.0f});
                f32x2 s;
                s.x = __builtin_amdgcn_sqrtf(t.x);           // v_sqrt_f32
                s.y = __builtin_amdgcn_sqrtf(t.y);
                acc2[k] = __builtin_elementwise_fma(s, (f32x2){jw, jw}, acc2[k]);
            }
        }
    }

    // ---- fold w_i per half, apply per-tile symmetry factors -------------
    f32x2 vv = iw2[0] * acc2[0];
#pragma unroll
    for (int k = 1; k < IR2; ++k)
        vv = __builtin_elementwise_fma(iw2[k], acc2[k], vv);
    float v = fmaf(fac0, vv.x, fac1 * vv.y);

    // ---- wave butterfly, cross-wave via LDS, one store per block --------
#pragma unroll
    for (int off = 32; off > 0; off >>= 1) v += __shfl_xor(v, off, 64);
    if (lane == 0) sred[wv] = v;
    __syncthreads();
    if (tid == 0) partials[bid] = sred[0] + sred[1] + sred[2] + sred[3];
}

extern "C" void kernel_launch(void* const* d_in, const int* in_sizes, int n_in,
                              void* d_out, int out_size, void* d_ws, size_t ws_size,
                              hipStream_t stream) {
    const float* inputs = (const float*)d_in[0];   // (4, 2, 8192) f32
    const float* coords = (const float*)d_in[1];   // (4, 8192, 3) f32
    float* out = (float*)d_out;                    // scalar f32
    char* ws = (char*)d_ws;
    float4* pts = (float4*)(ws + WS_PTS_OFF);
    float* wts = (float*)(ws + WS_W_OFF);
    float* partials = (float*)(ws + WS_PART_OFF);

    KUNi_prep<<<NPTS / 256, 256, 0, stream>>>(inputs, coords, pts, wts);
    KUNi_dpp_kernel<<<TOTAL_BLOCKS, 256, 0, stream>>>(pts, wts, partials);
    KUNi_finalize<<<1, 256, 0, stream>>>(partials, out);
}

// Round 15
// 86.232 us; speedup vs baseline: 1.0960x; 1.0199x over previous
//
#include <hip/hip_runtime.h>

#define NFULL 8192
#define BATCH 4
#define NPTS (NFULL * BATCH)             // 32768 points total
#define TT 256                           // square tile side
#define NT (NFULL / TT)                  // 32 tiles per dim
#define JOBS_PER_B (NT * (NT + 1) / 2)   // 528 triangular tile pairs
#define TOTAL_JOBS (BATCH * JOBS_PER_B)  // 2112
#define IR 4                             // i-points per lane (64*4 = 256 = TT)
#define JW 64                            // j-points per wave (4 waves * 64 = TT)
#define LAMBDA 0.001

typedef float f32x2 __attribute__((ext_vector_type(2)));

// ws layout: float4 pts | float w | float partials  (~648 KB)
#define WS_PTS_OFF   0
#define WS_W_OFF     (NPTS * 16)
#define WS_PART_OFF  (WS_W_OFF + NPTS * 4)

// ---- prep: materialize per-point derived values once --------------------
__global__ __launch_bounds__(256)
void KUNi_prep(const float* __restrict__ inputs,
               const float* __restrict__ coords,
               float4* __restrict__ pts,
               float* __restrict__ wts) {
    const int idx = blockIdx.x * 256 + threadIdx.x;    // 0..NPTS-1
    const int b = idx >> 13;                           // /8192
    const int n = idx & (NFULL - 1);
    const float* cp = coords + (size_t)idx * 3;
    const float x = cp[0], y = cp[1], z = cp[2];
    const float sq = fmaf(x, x, fmaf(y, y, z * z));
    const float a0 = inputs[(size_t)b * 2 * NFULL + n];
    const float a1 = inputs[(size_t)b * 2 * NFULL + NFULL + n];
    const float w = 1.0f / (1.0f + __expf(a0 - a1));   // softmax(C=2)[1]
    pts[idx] = make_float4(x, y, z, sq);
    wts[idx] = w;
}

__global__ void KUNi_finalize(const float* __restrict__ partials,
                              float* __restrict__ out) {
    const int tid = threadIdx.x;          // 256
    const int lane = tid & 63, wv = tid >> 6;
    double s = 0.0;
    for (int i = tid; i < TOTAL_JOBS; i += 256) s += (double)partials[i];
#pragma unroll
    for (int off = 32; off > 0; off >>= 1) s += __shfl_xor(s, off, 64);
    __shared__ double sd[4];
    if (lane == 0) sd[wv] = s;
    __syncthreads();
    if (tid == 0) {
        const double scale = LAMBDA / ((double)BATCH * (double)NFULL * (double)NFULL);
        out[0] = (float)((sd[0] + sd[1] + sd[2] + sd[3]) * scale);
    }
}

__device__ __forceinline__ int tri_off(int t) {        // row start of row t
    return t * (2 * NT + 1 - t) / 2;
}

// f32x2 = TWO ADJACENT J-POINTS: all j-operands are contiguous ds_read_b64
// from SoA LDS (zero splat movs in the loop); i-side values are pre-dup'd
// registers built once in the prologue.
__global__ __launch_bounds__(256)
void KUNi_dpp_kernel(const float4* __restrict__ pts,
                     const float* __restrict__ wts,
                     float* __restrict__ partials) {
    __shared__ float sjx[TT], sjy[TT], sjz[TT], sjsq[TT], sjw[TT];
    __shared__ float sred[4];

    const int tid = threadIdx.x;         // 0..255
    const int lane = tid & 63;
    const int wv = tid >> 6;             // wave 0..3
    const int bid = blockIdx.x;          // 0..2111
    const int b = bid / JOBS_PER_B;
    const int p = bid - b * JOBS_PER_B;

    // closed-form triangular decode (ti <= tj), float sqrt + exact fixup
    const float q = (float)(2 * NT + 1); // 65
    int ti = (int)floorf((q - sqrtf(fmaf(-8.0f, (float)p, q * q))) * 0.5f);
    if (p < tri_off(ti)) --ti;
    else if (p >= tri_off(ti + 1)) ++ti;
    const int tj = ti + (p - tri_off(ti));
    const int base = b * NFULL;

    // ---- stage j-tile into SoA LDS with -2 prescale ---------------------
    {
        const float4 jp = pts[base + tj * TT + tid];
        sjx[tid] = -2.0f * jp.x;
        sjy[tid] = -2.0f * jp.y;
        sjz[tid] = -2.0f * jp.z;
        sjsq[tid] = jp.w;
        sjw[tid] = wts[base + tj * TT + tid];
    }

    // ---- i-side: IR points per lane, each value pre-duplicated ----------
    f32x2 ixd[IR], iyd[IR], izd[IR], isqd[IR], acc2[IR];
    float iw[IR];
    const int ibase = base + ti * TT + lane;
#pragma unroll
    for (int k = 0; k < IR; ++k) {
        const float4 p0 = pts[ibase + k * 64];
        ixd[k]  = (f32x2){p0.x, p0.x};
        iyd[k]  = (f32x2){p0.y, p0.y};
        izd[k]  = (f32x2){p0.z, p0.z};
        isqd[k] = (f32x2){p0.w, p0.w};
        iw[k]   = wts[ibase + k * 64];
        acc2[k] = (f32x2){0.0f, 0.0f};
    }

    __syncthreads();

    // ---- wave's 64-j chunk, 2 j's per iteration -------------------------
    const int j0 = wv * JW;
#pragma unroll 4
    for (int g = 0; g < JW / 2; ++g) {
        const int jb = j0 + 2 * g;
        const f32x2 jx2  = *(const f32x2*)&sjx[jb];    // ds_read_b64, uniform
        const f32x2 jy2  = *(const f32x2*)&sjy[jb];
        const f32x2 jz2  = *(const f32x2*)&sjz[jb];
        const f32x2 jsq2 = *(const f32x2*)&sjsq[jb];
        const f32x2 jw2  = *(const f32x2*)&sjw[jb];
#pragma unroll
        for (int k = 0; k < IR; ++k) {
            f32x2 t = isqd[k] + jsq2;                      // v_pk_add_f32
            t = __builtin_elementwise_fma(ixd[k], jx2, t); // v_pk_fma_f32
            t = __builtin_elementwise_fma(iyd[k], jy2, t);
            t = __builtin_elementwise_fma(izd[k], jz2, t);
            t = __builtin_elementwise_max(t, (f32x2){0.0f, 0.0f});
            f32x2 s;
            s.x = __builtin_amdgcn_sqrtf(t.x);             // v_sqrt_f32
            s.y = __builtin_amdgcn_sqrtf(t.y);
            acc2[k] = __builtin_elementwise_fma(s, jw2, acc2[k]);
        }
    }

    // ---- fold w_i (acc halves are j-even/j-odd partial sums) ------------
    float v = 0.0f;
#pragma unroll
    for (int k = 0; k < IR; ++k) v = fmaf(iw[k], acc2[k].x + acc2[k].y, v);
    if (ti != tj) v *= 2.0f;

    // ---- wave butterfly, cross-wave via LDS, one store per block --------
#pragma unroll
    for (int off = 32; off > 0; off >>= 1) v += __shfl_xor(v, off, 64);
    if (lane == 0) sred[wv] = v;
    __syncthreads();
    if (tid == 0) partials[bid] = sred[0] + sred[1] + sred[2] + sred[3];
}

extern "C" void kernel_launch(void* const* d_in, const int* in_sizes, int n_in,
                              void* d_out, int out_size, void* d_ws, size_t ws_size,
                              hipStream_t stream) {
    const float* inputs = (const float*)d_in[0];   // (4, 2, 8192) f32
    const float* coords = (const float*)d_in[1];   // (4, 8192, 3) f32
    float* out = (float*)d_out;                    // scalar f32
    char* ws = (char*)d_ws;
    float4* pts = (float4*)(ws + WS_PTS_OFF);
    float* wts = (float*)(ws + WS_W_OFF);
    float* partials = (float*)(ws + WS_PART_OFF);

    KUNi_prep<<<NPTS / 256, 256, 0, stream>>>(inputs, coords, pts, wts);
    KUNi_dpp_kernel<<<TOTAL_JOBS, 256, 0, stream>>>(pts, wts, partials);
    KUNi_finalize<<<1, 256, 0, stream>>>(partials, out);
}